// Round 11
// baseline (309.534 us; speedup 1.0000x reference)
//
#include <hip/hip_runtime.h>
#include <hip/hip_bf16.h>
#include <math.h>

// Problem constants
#define BZ   8
#define DD   512
#define LL   2048
#define HH   8
#define MM   1024
#define DH   64
#define NN   (BZ * LL)               // 16384 rows per head
#define TOTAL_ELEMS (HH * NN * DH)   // 8388608

// d_out layout (floats): [z_q (8388608)] [vq_loss (1)] [indices (131072)] [codebooks (524288)]
#define OFF_ZQ   0
#define OFF_LOSS 8388608
#define OFF_IDX  8388609
#define OFF_CB   8519681

// d_ws layout (R10 proved ws_size >= 35.7MB; we need ~21MB):
// [sse 64B][cb_hi 1MB][cb_lo 1MB][zt bf16 16MB][sums fp32 2MB][counts fp32 32KB]
#define WS_SSE_BYTE   0
#define WS_CBHI_BYTE  64
#define WS_CBLO_BYTE  (64 + 1048576)
#define WS_ZT_BYTE    (64 + 2097152)
#define WS_SUMS_BYTE  (WS_ZT_BYTE + 16777216)
#define WS_CNTS_BYTE  (WS_SUMS_BYTE + 2097152)

typedef __attribute__((ext_vector_type(8))) short short8;
typedef __attribute__((ext_vector_type(4))) float float4v;

__device__ __forceinline__ unsigned short f2bf(float f) {
    unsigned int u = __builtin_bit_cast(unsigned int, f);
    u += 0x7FFFu + ((u >> 16) & 1u);          // RNE
    return (unsigned short)(u >> 16);
}
__device__ __forceinline__ float bf2f(unsigned short s) {
    unsigned int u = ((unsigned int)s) << 16;
    return __builtin_bit_cast(float, u);
}

__device__ __forceinline__ void gload16(const short* g, short* l) {
    __builtin_amdgcn_global_load_lds(
        (const __attribute__((address_space(1))) unsigned int*)g,
        (__attribute__((address_space(3))) unsigned int*)l, 16, 0, 0);
}

// Prep: fp32 codebook -> bf16 hi/lo planes, 16B chunks XOR-swizzled within each
// 128B row so unpadded LDS tiles read conflict-free.
__global__ __launch_bounds__(256) void cvt_cb_kernel(
    const float* __restrict__ cb, short* __restrict__ hip_, short* __restrict__ lop_)
{
    const int tid = blockIdx.x * 256 + threadIdx.x;
    const int c   = tid & 7;
    const int row = tid >> 3;                          // h*MM + m
    const float* __restrict__ src = cb + (size_t)row * DH + c * 8;
    short hs[8], ls[8];
#pragma unroll
    for (int j = 0; j < 8; ++j) {
        const float f = src[j];
        const unsigned short hv = f2bf(f);
        hs[j] = (short)hv;
        ls[j] = (short)f2bf(f - bf2f(hv));
    }
    const int dst = row * DH + ((c ^ (row & 7)) * 8);
    *(short8*)&hip_[dst] = *(short8*)hs;
    *(short8*)&lop_[dst] = *(short8*)ls;
}

// Kernel A: MFMA scan (hi/lo bf16) + fp64 rescreen + zq/idx/sse outputs.
// Also writes zt [H][64][N] bf16 (z hi) for the one-hot segment-sum GEMM.
__global__ __launch_bounds__(512) void vq_assign_kernel(
    const float* __restrict__ z,          // [B, D, L]
    const float* __restrict__ cb,         // [H, M, DH] fp32
    const short* __restrict__ cb_hi,      // bf16 hi, swizzled
    const short* __restrict__ cb_lo,      // bf16 lo, swizzled
    float* __restrict__ zq_out,
    float* __restrict__ idx_out,
    float* __restrict__ sse,
    short* __restrict__ zt)               // [H, 64, NN] bf16
{
    __shared__ __align__(16) short hi_lds[2][64 * DH];   // 2 x 8 KB
    __shared__ __align__(16) short lo_lds[2][64 * DH];   // 2 x 8 KB

    const int t    = threadIdx.x;
    const int h    = blockIdx.y;
    const int lane = t & 63;
    const int g    = lane >> 4;          // quad 0..3
    const int nloc = lane & 15;
    const int w    = t >> 6;             // wave 0..7

    const int r = blockIdx.x * 128 + w * 16 + nloc;
    const int b = r >> 11;
    const int l = r & (LL - 1);
    const float* __restrict__ zbase = z + ((size_t)(b * DD + h * DH) * LL + l);

    // B-fragment z values: zv[j] <-> k=g*8+j, zv[8+j] <-> k=32+g*8+j.
    float zv[16] __attribute__((aligned(16)));
#pragma unroll
    for (int j = 0; j < 8; ++j) zv[j]     = zbase[(size_t)(g * 8 + j) * LL];
#pragma unroll
    for (int j = 0; j < 8; ++j) zv[8 + j] = zbase[(size_t)(32 + g * 8 + j) * LL];

    short bh[16], bl[16];
#pragma unroll
    for (int j = 0; j < 16; ++j) {
        const unsigned short hv = f2bf(zv[j]);
        bh[j] = (short)hv;
        bl[j] = (short)f2bf(zv[j] - bf2f(hv));
    }
    // zt write: zt[(h*64 + k)*NN + r] = bf16hi(z). Quad-contiguous 32B stores.
    {
        short* __restrict__ zth = zt + (size_t)h * 64 * NN;
#pragma unroll
        for (int j = 0; j < 8; ++j) {
            zth[(size_t)(g * 8 + j) * NN + r]      = bh[j];
            zth[(size_t)(32 + g * 8 + j) * NN + r] = bh[8 + j];
        }
    }
    const short8 Bh0 = *(short8*)&bh[0], Bh1 = *(short8*)&bh[8];
    const short8 Bl0 = *(short8*)&bl[0], Bl1 = *(short8*)&bl[8];

    const short* __restrict__ gh = cb_hi + (size_t)h * MM * DH;
    const short* __restrict__ gl = cb_lo + (size_t)h * MM * DH;

    auto stage = [&](int mt, int buf) {
        const short* sh = gh + (size_t)mt * 64 * DH;
        const short* sl = gl + (size_t)mt * 64 * DH;
        gload16(sh + t * 8, &hi_lds[buf][t * 8]);
        gload16(sl + t * 8, &lo_lds[buf][t * 8]);
    };

    stage(0, 0);

    float b1c[4], b2c[4];
    int   i1c[4], i2c[4];
#pragma unroll
    for (int s = 0; s < 4; ++s) { b1c[s] = -1e30f; b2c[s] = -1e30f; i1c[s] = 0; i2c[s] = 0; }

    const int sw8 = nloc & 7;

    for (int mt = 0; mt < MM / 64; ++mt) {
        __syncthreads();
        if (mt + 1 < MM / 64) stage(mt + 1, (mt + 1) & 1);
        const int buf = mt & 1;

#pragma unroll
        for (int s = 0; s < 4; ++s) {
            const short* hrow = &hi_lds[buf][(s * 16 + nloc) * DH];
            const short* lrow = &lo_lds[buf][(s * 16 + nloc) * DH];
            const short8 Ah0 = *(const short8*)&hrow[((g)     ^ sw8) * 8];
            const short8 Ah1 = *(const short8*)&hrow[((g + 4) ^ sw8) * 8];
            const short8 Al0 = *(const short8*)&lrow[((g)     ^ sw8) * 8];
            const short8 Al1 = *(const short8*)&lrow[((g + 4) ^ sw8) * 8];

            float4v acc = {0.f, 0.f, 0.f, 0.f};
            acc = __builtin_amdgcn_mfma_f32_16x16x32_bf16(Ah0, Bh0, acc, 0, 0, 0);
            acc = __builtin_amdgcn_mfma_f32_16x16x32_bf16(Ah1, Bh1, acc, 0, 0, 0);
            acc = __builtin_amdgcn_mfma_f32_16x16x32_bf16(Ah0, Bl0, acc, 0, 0, 0);
            acc = __builtin_amdgcn_mfma_f32_16x16x32_bf16(Ah1, Bl1, acc, 0, 0, 0);
            acc = __builtin_amdgcn_mfma_f32_16x16x32_bf16(Al0, Bh0, acc, 0, 0, 0);
            acc = __builtin_amdgcn_mfma_f32_16x16x32_bf16(Al1, Bh1, acc, 0, 0, 0);

            const int mbase = mt * 64 + s * 16 + g * 4;
#pragma unroll
            for (int reg = 0; reg < 4; ++reg) {
                const float v = acc[reg];
                const int   m = mbase + reg;
                const bool gt1 = v > b1c[s];
                const bool gt2 = v > b2c[s];
                b2c[s] = gt1 ? b1c[s] : (gt2 ? v : b2c[s]);
                i2c[s] = gt1 ? i1c[s] : (gt2 ? m : i2c[s]);
                b1c[s] = gt1 ? v : b1c[s];
                i1c[s] = gt1 ? m : i1c[s];
            }
        }
    }

    float b1 = b1c[0], b2 = b2c[0];
    int   i1 = i1c[0], i2 = i2c[0];
#pragma unroll
    for (int s = 1; s < 4; ++s) {
        const float ob1 = b1c[s], ob2 = b2c[s];
        const int   oi1 = i1c[s], oi2 = i2c[s];
        const bool agt = (b1 > ob1) || (b1 == ob1 && i1 < oi1);
        const float w1 = agt ? b1 : ob1;  const int wi1 = agt ? i1 : oi1;
        const float l1 = agt ? ob1 : b1;  const int li1 = agt ? oi1 : i1;
        const float w2 = agt ? b2 : ob2;  const int wi2 = agt ? i2 : oi2;
        const bool sgt = (l1 > w2) || (l1 == w2 && li1 < wi2);
        b1 = w1;  i1 = wi1;
        b2 = sgt ? l1 : w2;  i2 = sgt ? li1 : wi2;
    }
#pragma unroll
    for (int off = 16; off <= 32; off <<= 1) {
        float ob1 = __shfl_xor(b1, off, 64);
        int   oi1 = __shfl_xor(i1, off, 64);
        float ob2 = __shfl_xor(b2, off, 64);
        int   oi2 = __shfl_xor(i2, off, 64);
        const bool agt = (b1 > ob1) || (b1 == ob1 && i1 < oi1);
        const float w1  = agt ? b1 : ob1;  const int wi1 = agt ? i1 : oi1;
        const float l1  = agt ? ob1 : b1;  const int li1 = agt ? oi1 : i1;
        const float w2  = agt ? b2 : ob2;  const int wi2 = agt ? i2 : oi2;
        const bool sgt = (l1 > w2) || (l1 == w2 && li1 < wi2);
        b1 = w1;  i1 = wi1;
        b2 = sgt ? l1 : w2;  i2 = sgt ? li1 : wi2;
    }

    // Exact fp64 rescreen of the two candidates (global fp32), reusing zv.
    const float* __restrict__ cbh = cb + (size_t)h * MM * DH;
    const float* __restrict__ c1  = cbh + (size_t)i1 * DH;
    const float* __restrict__ c2  = cbh + (size_t)i2 * DH;
    double d1 = 0.0, d2 = 0.0;
#pragma unroll
    for (int j = 0; j < 8; ++j) {
        const int k0 = g * 8 + j, k1 = 32 + g * 8 + j;
        d1 = fma((double)zv[j],     (double)c1[k0], d1);
        d1 = fma((double)zv[8 + j], (double)c1[k1], d1);
        d2 = fma((double)zv[j],     (double)c2[k0], d2);
        d2 = fma((double)zv[8 + j], (double)c2[k1], d2);
    }
    d1 += __shfl_xor(d1, 16, 64);  d1 += __shfl_xor(d1, 32, 64);
    d2 += __shfl_xor(d2, 16, 64);  d2 += __shfl_xor(d2, 32, 64);
    const int best = (d2 > d1 || (d2 == d1 && i2 < i1)) ? i2 : i1;

    const float* __restrict__ cq  = cbh + (size_t)best * DH;
    float* __restrict__ zqp  = zq_out + ((size_t)(b * DD + h * DH) * LL + l);
    float err = 0.f;
#pragma unroll
    for (int j = 0; j < 8; ++j) {
        const int k0 = g * 8 + j, k1 = 32 + g * 8 + j;
        const float q0 = cq[k0], q1 = cq[k1];
        zqp[(size_t)k0 * LL] = q0;
        zqp[(size_t)k1 * LL] = q1;
        const float e0 = zv[j] - q0, e1 = zv[8 + j] - q1;
        err = fmaf(e0, e0, err);
        err = fmaf(e1, e1, err);
    }
    if (g == 0) idx_out[((size_t)b * HH + h) * LL + l] = (float)best;
#pragma unroll
    for (int off = 32; off; off >>= 1) err += __shfl_xor(err, off, 64);
    if (lane == 0) atomicAdd(sse, err);
}

// One-hot MFMA segment-sum: sums[h,m,:] = sum_{n: idx[n]==m} zt[h,:,n].
// Block = (mrange 64 codes, nrange 4096 rows, head). Wave w owns 16 codes.
// zt n-chunks double-buffered in LDS via DMA (XOR-swizzled 16B chunks).
__global__ __launch_bounds__(256) void vq_segsum_kernel(
    const float* __restrict__ idx,      // [B, H, L] as float
    const short* __restrict__ zt,       // [H, 64, NN] bf16
    float* __restrict__ sums,           // [H*M, 64] fp32 (atomic)
    float* __restrict__ counts)         // [H*M] fp32 (atomic)
{
    __shared__ __align__(16) short ztl[2][64 * 64];   // 2 x 8 KB
    __shared__ int hist[64];

    const int t    = threadIdx.x;
    const int lane = t & 63;
    const int g    = lane >> 4;
    const int nloc = lane & 15;
    const int w    = t >> 6;             // wave 0..3

    const int mb  = blockIdx.x * 64;     // code range [mb, mb+64)
    const int nb0 = blockIdx.y * 4096;   // row range
    const int h   = blockIdx.z;

    if (t < 64) hist[t] = 0;
    __syncthreads();

    // Histogram of this n-range for codes [mb, mb+64).
    {
        const int n0 = nb0 + t * 16;     // 16 consecutive n, same b (16 | 2048)
        const int b  = n0 >> 11;
        const int l0 = n0 & (LL - 1);
        const float* __restrict__ ip = idx + ((size_t)(b * HH + h)) * LL + l0;
#pragma unroll
        for (int i = 0; i < 16; ++i) {
            const int m = (int)ip[i] - mb;
            if ((unsigned)m < 64u) atomicAdd(&hist[m], 1);
        }
    }

    const short* __restrict__ zth = zt + (size_t)h * 64 * NN;

    // Stage 64 n-cols x 64 k-rows of zt: 512 16B chunks, XOR-swizzled per row.
    auto stage = [&](int is, int buf) {
        const size_t nb = (size_t)(nb0 + is * 64);
#pragma unroll
        for (int q = 0; q < 2; ++q) {
            const int id = q * 256 + t;
            const int kr = id >> 3;
            const int cp = id & 7;
            const int cs = cp ^ (kr & 7);
            gload16(zth + (size_t)kr * NN + nb + cs * 8, &ztl[buf][id * 8]);
        }
    };

    stage(0, 0);

    float4v acc[4];
#pragma unroll
    for (int ct = 0; ct < 4; ++ct) acc[ct] = (float4v){0.f, 0.f, 0.f, 0.f};

    const float fmc = (float)(mb + w * 16 + nloc);   // this lane's code (A-row)

    for (int is = 0; is < 64; ++is) {
        __syncthreads();                 // drains tile is's DMA
        if (is + 1 < 64) stage(is + 1, (is + 1) & 1);
        const int buf = is & 1;

        const int n0 = nb0 + is * 64;
        const int b  = n0 >> 11;
        const int l0 = n0 & (LL - 1);
        const float* __restrict__ ipb = idx + ((size_t)(b * HH + h)) * LL + l0;

#pragma unroll
        for (int kc = 0; kc < 2; ++kc) {
            // One-hot A-frag: A[m=nloc][r=g*8+j] = (idx[n0+kc*32+g*8+j] == code)
            const float4 ia = *(const float4*)(ipb + kc * 32 + g * 8);
            const float4 ib = *(const float4*)(ipb + kc * 32 + g * 8 + 4);
            short av[8];
#pragma unroll
            for (int j = 0; j < 4; ++j) {
                av[j]     = ((&ia.x)[j] == fmc) ? (short)0x3F80 : (short)0;
                av[4 + j] = ((&ib.x)[j] == fmc) ? (short)0x3F80 : (short)0;
            }
            const short8 Af = *(short8*)av;
#pragma unroll
            for (int ct = 0; ct < 4; ++ct) {
                const int kz = ct * 16 + nloc;
                const short8 Bf = *(const short8*)
                    &ztl[buf][kz * 64 + (((kc * 4 + g) ^ (kz & 7)) * 8)];
                acc[ct] = __builtin_amdgcn_mfma_f32_16x16x32_bf16(Af, Bf, acc[ct], 0, 0, 0);
            }
        }
    }

    // acc: code m = mb + w*16 + g*4 + reg, feature kz = ct*16 + nloc.
#pragma unroll
    for (int ct = 0; ct < 4; ++ct)
#pragma unroll
        for (int reg = 0; reg < 4; ++reg)
            atomicAdd(&sums[((size_t)h * MM + mb + w * 16 + g * 4 + reg) * DH
                            + ct * 16 + nloc], acc[ct][reg]);

    __syncthreads();
    if (t < 64) atomicAdd(&counts[h * MM + mb + t], (float)hist[t]);
}

// Final slerp + rms_norm update from sums/counts. One wave per code.
__global__ __launch_bounds__(256) void vq_update_kernel(
    const float* __restrict__ cb,
    const float* __restrict__ sums,
    const float* __restrict__ counts,
    const float* __restrict__ sse,
    float* __restrict__ cb_out,
    float* __restrict__ loss_out)
{
    if (blockIdx.x == 0 && threadIdx.x == 0) {
        loss_out[0] = 1.25f * sse[0] / (float)TOTAL_ELEMS;
    }
    const int row  = blockIdx.x * 4 + (threadIdx.x >> 6);   // h*MM + m
    const int lane = threadIdx.x & 63;

    const float cnt  = counts[row];
    const float c    = cb[(size_t)row * DH + lane];
    const float mean = sums[(size_t)row * DH + lane] / fmaxf(cnt, 1.0f);

    float dot = mean * c;
    float nl  = mean * mean;
    float nh  = c * c;
#pragma unroll
    for (int off = 32; off; off >>= 1) {
        dot += __shfl_xor(dot, off, 64);
        nl  += __shfl_xor(nl,  off, 64);
        nh  += __shfl_xor(nh,  off, 64);
    }

    float cosv = dot / fmaxf(sqrtf(nl) * sqrtf(nh), 1e-8f);
    cosv = fminf(fmaxf(cosv, -0.9999999f), 0.9999999f);
    const float omega = acosf(cosv);
    const float so    = sinf(omega);
    float outv = (mean * sinf(0.01f * omega) + c * sinf(0.99f * omega)) / so;

    float ms = outv * outv;
#pragma unroll
    for (int off = 32; off; off >>= 1) ms += __shfl_xor(ms, off, 64);
    ms = ms * (1.0f / (float)DH) + 1.1920929e-07f;
    const float normed = outv / sqrtf(ms);

    cb_out[(size_t)row * DH + lane] = (cnt > 0.f) ? normed : c;
}

extern "C" void kernel_launch(void* const* d_in, const int* in_sizes, int n_in,
                              void* d_out, int out_size, void* d_ws, size_t ws_size,
                              hipStream_t stream) {
    const float* z  = (const float*)d_in[0];
    const float* cb = (const float*)d_in[1];
    float* out = (float*)d_out;
    char*  wsb = (char*)d_ws;
    float* sse    = (float*)(wsb + WS_SSE_BYTE);
    short* cb_hi  = (short*)(wsb + WS_CBHI_BYTE);
    short* cb_lo  = (short*)(wsb + WS_CBLO_BYTE);
    short* zt     = (short*)(wsb + WS_ZT_BYTE);
    float* sums   = (float*)(wsb + WS_SUMS_BYTE);
    float* counts = (float*)(wsb + WS_CNTS_BYTE);

    hipMemsetAsync(sse, 0, 64, stream);
    hipMemsetAsync(sums, 0, 2097152 + 32768, stream);   // sums + counts

    cvt_cb_kernel<<<(HH * MM * DH / 8) / 256, 256, 0, stream>>>(cb, cb_hi, cb_lo);

    dim3 gridA(NN / 128, HH);   // (128, 8) = 1024 blocks x 8 waves
    vq_assign_kernel<<<gridA, 512, 0, stream>>>(
        z, cb, cb_hi, cb_lo,
        out + OFF_ZQ, out + OFF_IDX, sse, zt);

    dim3 gridS(MM / 64, 4, HH); // (16, 4, 8) = 512 blocks x 4 waves
    vq_segsum_kernel<<<gridS, 256, 0, stream>>>(
        out + OFF_IDX, zt, sums, counts);

    dim3 gridU((HH * MM) / 4);  // 2048 blocks
    vq_update_kernel<<<gridU, 256, 0, stream>>>(
        cb, sums, counts, sse,
        out + OFF_CB, out + OFF_LOSS);
}

// Round 12
// 264.814 us; speedup vs baseline: 1.1689x; 1.1689x over previous
//
#include <hip/hip_runtime.h>
#include <hip/hip_bf16.h>
#include <math.h>

// Problem constants
#define BZ   8
#define DD   512
#define LL   2048
#define HH   8
#define MM   1024
#define DH   64
#define NN   (BZ * LL)               // 16384 rows per head
#define TOTAL_ELEMS (HH * NN * DH)   // 8388608

// d_out layout (floats): [z_q (8388608)] [vq_loss (1)] [indices (131072)] [codebooks (524288)]
#define OFF_ZQ   0
#define OFF_LOSS 8388608
#define OFF_IDX  8388609
#define OFF_CB   8519681

// d_ws layout (proven ws_size >= 35,651,712 in R10):
// [sse 64B][cb_hi 1MB][cb_lo 1MB][zs fp32 33.5MB]
// Sort arrays ALIAS the cb_hi plane (A is done with it before they're written):
//   counts int[8192] @+64 | offsets int[8192] @+64+32K | cursors int[8192] @+64+64K
//   rowlist ushort[131072] @+64+96K   (total 352KB < 1MB)
#define WS_CBHI_BYTE  64
#define WS_CBLO_BYTE  (64 + 1048576)
#define WS_ZS_BYTE    (64 + 2097152)
#define WS_CNT_BYTE   64
#define WS_OFF_BYTE   (64 + 32768)
#define WS_CUR_BYTE   (64 + 65536)
#define WS_RL_BYTE    (64 + 98304)

typedef __attribute__((ext_vector_type(8))) short short8;
typedef __attribute__((ext_vector_type(4))) float float4v;

__device__ __forceinline__ unsigned short f2bf(float f) {
    unsigned int u = __builtin_bit_cast(unsigned int, f);
    u += 0x7FFFu + ((u >> 16) & 1u);          // RNE
    return (unsigned short)(u >> 16);
}
__device__ __forceinline__ float bf2f(unsigned short s) {
    unsigned int u = ((unsigned int)s) << 16;
    return __builtin_bit_cast(float, u);
}

__device__ __forceinline__ void gload16(const short* g, short* l) {
    __builtin_amdgcn_global_load_lds(
        (const __attribute__((address_space(1))) unsigned int*)g,
        (__attribute__((address_space(3))) unsigned int*)l, 16, 0, 0);
}

// Prep: fp32 codebook -> bf16 hi/lo planes, 16B chunks XOR-swizzled within each
// 128B row so unpadded LDS tiles read conflict-free.
__global__ __launch_bounds__(256) void cvt_cb_kernel(
    const float* __restrict__ cb, short* __restrict__ hip_, short* __restrict__ lop_)
{
    const int tid = blockIdx.x * 256 + threadIdx.x;
    const int c   = tid & 7;
    const int row = tid >> 3;                          // h*MM + m
    const float* __restrict__ src = cb + (size_t)row * DH + c * 8;
    short hs[8], ls[8];
#pragma unroll
    for (int j = 0; j < 8; ++j) {
        const float f = src[j];
        const unsigned short hv = f2bf(f);
        hs[j] = (short)hv;
        ls[j] = (short)f2bf(f - bf2f(hv));
    }
    const int dst = row * DH + ((c ^ (row & 7)) * 8);
    *(short8*)&hip_[dst] = *(short8*)hs;
    *(short8*)&lop_[dst] = *(short8*)ls;
}

// Kernel A (R10 config): MFMA scan (hi/lo bf16) + fp64 rescreen; writes
// zq, idx, sse, and z_split [H,N,64] fp32 for the counting-sort gather.
__global__ __launch_bounds__(512) void vq_assign_kernel(
    const float* __restrict__ z,          // [B, D, L]
    const float* __restrict__ cb,         // [H, M, DH] fp32
    const short* __restrict__ cb_hi,      // bf16 hi, swizzled
    const short* __restrict__ cb_lo,      // bf16 lo, swizzled
    float* __restrict__ zq_out,
    float* __restrict__ idx_out,
    float* __restrict__ sse,
    float* __restrict__ zs)               // [H, N, DH]
{
    __shared__ __align__(16) short hi_lds[2][64 * DH];   // 2 x 8 KB
    __shared__ __align__(16) short lo_lds[2][64 * DH];   // 2 x 8 KB

    const int t    = threadIdx.x;
    const int h    = blockIdx.y;
    const int lane = t & 63;
    const int g    = lane >> 4;          // quad 0..3
    const int nloc = lane & 15;
    const int w    = t >> 6;             // wave 0..7

    const int r = blockIdx.x * 128 + w * 16 + nloc;
    const int b = r >> 11;
    const int l = r & (LL - 1);
    const float* __restrict__ zbase = z + ((size_t)(b * DD + h * DH) * LL + l);

    // B-fragment z values: zv[j] <-> k=g*8+j, zv[8+j] <-> k=32+g*8+j.
    float zv[16] __attribute__((aligned(16)));
#pragma unroll
    for (int j = 0; j < 8; ++j) zv[j]     = zbase[(size_t)(g * 8 + j) * LL];
#pragma unroll
    for (int j = 0; j < 8; ++j) zv[8 + j] = zbase[(size_t)(32 + g * 8 + j) * LL];

    // z_split write: 16B chunks, quad-contiguous.
    {
        float* __restrict__ zr_ = zs + ((size_t)h * NN + r) * DH;
        *(float4*)&zr_[g * 8]          = *(const float4*)&zv[0];
        *(float4*)&zr_[g * 8 + 4]      = *(const float4*)&zv[4];
        *(float4*)&zr_[32 + g * 8]     = *(const float4*)&zv[8];
        *(float4*)&zr_[32 + g * 8 + 4] = *(const float4*)&zv[12];
    }

    short bh[16], bl[16];
#pragma unroll
    for (int j = 0; j < 16; ++j) {
        const unsigned short hv = f2bf(zv[j]);
        bh[j] = (short)hv;
        bl[j] = (short)f2bf(zv[j] - bf2f(hv));
    }
    const short8 Bh0 = *(short8*)&bh[0], Bh1 = *(short8*)&bh[8];
    const short8 Bl0 = *(short8*)&bl[0], Bl1 = *(short8*)&bl[8];

    const short* __restrict__ gh = cb_hi + (size_t)h * MM * DH;
    const short* __restrict__ gl = cb_lo + (size_t)h * MM * DH;

    auto stage = [&](int mt, int buf) {
        const short* sh = gh + (size_t)mt * 64 * DH;
        const short* sl = gl + (size_t)mt * 64 * DH;
        gload16(sh + t * 8, &hi_lds[buf][t * 8]);
        gload16(sl + t * 8, &lo_lds[buf][t * 8]);
    };

    stage(0, 0);

    float b1c[4], b2c[4];
    int   i1c[4], i2c[4];
#pragma unroll
    for (int s = 0; s < 4; ++s) { b1c[s] = -1e30f; b2c[s] = -1e30f; i1c[s] = 0; i2c[s] = 0; }

    const int sw8 = nloc & 7;

    for (int mt = 0; mt < MM / 64; ++mt) {
        __syncthreads();
        if (mt + 1 < MM / 64) stage(mt + 1, (mt + 1) & 1);
        const int buf = mt & 1;

#pragma unroll
        for (int s = 0; s < 4; ++s) {
            const short* hrow = &hi_lds[buf][(s * 16 + nloc) * DH];
            const short* lrow = &lo_lds[buf][(s * 16 + nloc) * DH];
            const short8 Ah0 = *(const short8*)&hrow[((g)     ^ sw8) * 8];
            const short8 Ah1 = *(const short8*)&hrow[((g + 4) ^ sw8) * 8];
            const short8 Al0 = *(const short8*)&lrow[((g)     ^ sw8) * 8];
            const short8 Al1 = *(const short8*)&lrow[((g + 4) ^ sw8) * 8];

            float4v acc = {0.f, 0.f, 0.f, 0.f};
            acc = __builtin_amdgcn_mfma_f32_16x16x32_bf16(Ah0, Bh0, acc, 0, 0, 0);
            acc = __builtin_amdgcn_mfma_f32_16x16x32_bf16(Ah1, Bh1, acc, 0, 0, 0);
            acc = __builtin_amdgcn_mfma_f32_16x16x32_bf16(Ah0, Bl0, acc, 0, 0, 0);
            acc = __builtin_amdgcn_mfma_f32_16x16x32_bf16(Ah1, Bl1, acc, 0, 0, 0);
            acc = __builtin_amdgcn_mfma_f32_16x16x32_bf16(Al0, Bh0, acc, 0, 0, 0);
            acc = __builtin_amdgcn_mfma_f32_16x16x32_bf16(Al1, Bh1, acc, 0, 0, 0);

            const int mbase = mt * 64 + s * 16 + g * 4;
#pragma unroll
            for (int reg = 0; reg < 4; ++reg) {
                const float v = acc[reg];
                const int   m = mbase + reg;
                const bool gt1 = v > b1c[s];
                const bool gt2 = v > b2c[s];
                b2c[s] = gt1 ? b1c[s] : (gt2 ? v : b2c[s]);
                i2c[s] = gt1 ? i1c[s] : (gt2 ? m : i2c[s]);
                b1c[s] = gt1 ? v : b1c[s];
                i1c[s] = gt1 ? m : i1c[s];
            }
        }
    }

    float b1 = b1c[0], b2 = b2c[0];
    int   i1 = i1c[0], i2 = i2c[0];
#pragma unroll
    for (int s = 1; s < 4; ++s) {
        const float ob1 = b1c[s], ob2 = b2c[s];
        const int   oi1 = i1c[s], oi2 = i2c[s];
        const bool agt = (b1 > ob1) || (b1 == ob1 && i1 < oi1);
        const float w1 = agt ? b1 : ob1;  const int wi1 = agt ? i1 : oi1;
        const float l1 = agt ? ob1 : b1;  const int li1 = agt ? oi1 : i1;
        const float w2 = agt ? b2 : ob2;  const int wi2 = agt ? i2 : oi2;
        const bool sgt = (l1 > w2) || (l1 == w2 && li1 < wi2);
        b1 = w1;  i1 = wi1;
        b2 = sgt ? l1 : w2;  i2 = sgt ? li1 : wi2;
    }
#pragma unroll
    for (int off = 16; off <= 32; off <<= 1) {
        float ob1 = __shfl_xor(b1, off, 64);
        int   oi1 = __shfl_xor(i1, off, 64);
        float ob2 = __shfl_xor(b2, off, 64);
        int   oi2 = __shfl_xor(i2, off, 64);
        const bool agt = (b1 > ob1) || (b1 == ob1 && i1 < oi1);
        const float w1  = agt ? b1 : ob1;  const int wi1 = agt ? i1 : oi1;
        const float l1  = agt ? ob1 : b1;  const int li1 = agt ? oi1 : i1;
        const float w2  = agt ? b2 : ob2;  const int wi2 = agt ? i2 : oi2;
        const bool sgt = (l1 > w2) || (l1 == w2 && li1 < wi2);
        b1 = w1;  i1 = wi1;
        b2 = sgt ? l1 : w2;  i2 = sgt ? li1 : wi2;
    }

    // Exact fp64 rescreen of the two candidates (global fp32), reusing zv.
    const float* __restrict__ cbh = cb + (size_t)h * MM * DH;
    const float* __restrict__ c1  = cbh + (size_t)i1 * DH;
    const float* __restrict__ c2  = cbh + (size_t)i2 * DH;
    double d1 = 0.0, d2 = 0.0;
#pragma unroll
    for (int j = 0; j < 8; ++j) {
        const int k0 = g * 8 + j, k1 = 32 + g * 8 + j;
        d1 = fma((double)zv[j],     (double)c1[k0], d1);
        d1 = fma((double)zv[8 + j], (double)c1[k1], d1);
        d2 = fma((double)zv[j],     (double)c2[k0], d2);
        d2 = fma((double)zv[8 + j], (double)c2[k1], d2);
    }
    d1 += __shfl_xor(d1, 16, 64);  d1 += __shfl_xor(d1, 32, 64);
    d2 += __shfl_xor(d2, 16, 64);  d2 += __shfl_xor(d2, 32, 64);
    const int best = (d2 > d1 || (d2 == d1 && i2 < i1)) ? i2 : i1;

    const float* __restrict__ cq  = cbh + (size_t)best * DH;
    float* __restrict__ zqp  = zq_out + ((size_t)(b * DD + h * DH) * LL + l);
    float err = 0.f;
#pragma unroll
    for (int j = 0; j < 8; ++j) {
        const int k0 = g * 8 + j, k1 = 32 + g * 8 + j;
        const float q0 = cq[k0], q1 = cq[k1];
        zqp[(size_t)k0 * LL] = q0;
        zqp[(size_t)k1 * LL] = q1;
        const float e0 = zv[j] - q0, e1 = zv[8 + j] - q1;
        err = fmaf(e0, e0, err);
        err = fmaf(e1, e1, err);
    }
    if (g == 0) idx_out[((size_t)b * HH + h) * LL + l] = (float)best;
#pragma unroll
    for (int off = 32; off; off >>= 1) err += __shfl_xor(err, off, 64);
    if (lane == 0) atomicAdd(sse, err);
}

// Counting sort step 1: per-head histogram + prefix scan -> counts/offsets/cursors.
__global__ __launch_bounds__(256) void vq_hist_kernel(
    const float* __restrict__ idx,      // [B, H, L] as float
    int* __restrict__ counts, int* __restrict__ offsets, int* __restrict__ cursors)
{
    __shared__ int hist[MM];
    const int t = threadIdx.x;
    const int h = blockIdx.x;
#pragma unroll
    for (int i = t; i < MM; i += 256) hist[i] = 0;
    __syncthreads();
#pragma unroll 1
    for (int b = 0; b < BZ; ++b) {
        const float* __restrict__ ip = idx + ((size_t)(b * HH + h)) * LL;
#pragma unroll 1
        for (int i = t; i < LL; i += 256) atomicAdd(&hist[(int)ip[i]], 1);
    }
    __syncthreads();
    if (t < 64) {
        int loc[16];
        int s = 0;
#pragma unroll
        for (int j = 0; j < 16; ++j) { loc[j] = s; s += hist[t * 16 + j]; }
        // exclusive scan of s across the 64 lanes
        int pre = s;
#pragma unroll
        for (int off = 1; off < 64; off <<= 1) {
            const int v = __shfl_up(pre, off, 64);
            if (t >= off) pre += v;
        }
        const int excl = pre - s;
#pragma unroll
        for (int j = 0; j < 16; ++j) {
            const int bin = t * 16 + j;
            const int o   = excl + loc[j];
            counts[h * MM + bin]  = hist[bin];
            offsets[h * MM + bin] = o;
            cursors[h * MM + bin] = o;
        }
    }
}

// Counting sort step 2: scatter row ids into per-code lists.
__global__ __launch_bounds__(256) void vq_scatter_kernel(
    const float* __restrict__ idx,
    int* __restrict__ cursors, unsigned short* __restrict__ rowlist)
{
    const int tid = blockIdx.x * 256 + threadIdx.x;    // over B*H*L
    const int m = (int)idx[tid];
    const int l = tid & (LL - 1);
    const int h = (tid >> 11) & (HH - 1);
    const int b = tid >> 14;
    const int n = b * LL + l;
    const int pos = atomicAdd(&cursors[h * MM + m], 1);
    rowlist[(size_t)h * NN + pos] = (unsigned short)n;
}

// Counting sort step 3: per-code gather (256B contiguous per row) + slerp update.
__global__ __launch_bounds__(256) void vq_gather_update_kernel(
    const float* __restrict__ zs,        // [H, N, DH] fp32
    const float* __restrict__ cb,        // [H, M, DH]
    const int* __restrict__ counts, const int* __restrict__ offsets,
    const unsigned short* __restrict__ rowlist,
    const float* __restrict__ sse,
    float* __restrict__ cb_out, float* __restrict__ loss_out)
{
    if (blockIdx.x == 0 && threadIdx.x == 0) {
        loss_out[0] = 1.25f * sse[0] / (float)TOTAL_ELEMS;
    }
    const int row  = blockIdx.x * 4 + (threadIdx.x >> 6);   // h*MM + m
    const int lane = threadIdx.x & 63;
    const int h    = row >> 10;

    const int cnt = counts[row];
    const int off = offsets[row];
    const unsigned short* __restrict__ rl = rowlist + (size_t)h * NN + off;
    const float* __restrict__ zsh = zs + (size_t)h * NN * DH + lane;

    float a0 = 0.f, a1 = 0.f, a2 = 0.f, a3 = 0.f;
    int i = 0;
    for (; i + 4 <= cnt; i += 4) {
        const int n0 = rl[i], n1 = rl[i + 1], n2 = rl[i + 2], n3 = rl[i + 3];
        a0 += zsh[(size_t)n0 * DH];
        a1 += zsh[(size_t)n1 * DH];
        a2 += zsh[(size_t)n2 * DH];
        a3 += zsh[(size_t)n3 * DH];
    }
    for (; i < cnt; ++i) a0 += zsh[(size_t)rl[i] * DH];
    const float acc = (a0 + a1) + (a2 + a3);

    const float cf   = (float)cnt;
    const float c    = cb[(size_t)row * DH + lane];
    const float mean = acc / fmaxf(cf, 1.0f);

    float dot = mean * c;
    float nl  = mean * mean;
    float nh  = c * c;
#pragma unroll
    for (int off2 = 32; off2; off2 >>= 1) {
        dot += __shfl_xor(dot, off2, 64);
        nl  += __shfl_xor(nl,  off2, 64);
        nh  += __shfl_xor(nh,  off2, 64);
    }

    float cosv = dot / fmaxf(sqrtf(nl) * sqrtf(nh), 1e-8f);
    cosv = fminf(fmaxf(cosv, -0.9999999f), 0.9999999f);
    const float omega = acosf(cosv);
    const float so    = sinf(omega);
    float outv = (mean * sinf(0.01f * omega) + c * sinf(0.99f * omega)) / so;

    float ms = outv * outv;
#pragma unroll
    for (int off2 = 32; off2; off2 >>= 1) ms += __shfl_xor(ms, off2, 64);
    ms = ms * (1.0f / (float)DH) + 1.1920929e-07f;
    const float normed = outv / sqrtf(ms);

    cb_out[(size_t)row * DH + lane] = (cnt > 0) ? normed : c;
}

extern "C" void kernel_launch(void* const* d_in, const int* in_sizes, int n_in,
                              void* d_out, int out_size, void* d_ws, size_t ws_size,
                              hipStream_t stream) {
    const float* z  = (const float*)d_in[0];
    const float* cb = (const float*)d_in[1];
    float* out = (float*)d_out;
    char*  wsb = (char*)d_ws;
    float*          sse     = (float*)wsb;
    short*          cb_hi   = (short*)(wsb + WS_CBHI_BYTE);
    short*          cb_lo   = (short*)(wsb + WS_CBLO_BYTE);
    float*          zs      = (float*)(wsb + WS_ZS_BYTE);
    int*            counts  = (int*)(wsb + WS_CNT_BYTE);    // aliases cb_hi (post-A)
    int*            offsets = (int*)(wsb + WS_OFF_BYTE);
    int*            cursors = (int*)(wsb + WS_CUR_BYTE);
    unsigned short* rowlist = (unsigned short*)(wsb + WS_RL_BYTE);

    hipMemsetAsync(sse, 0, 64, stream);

    cvt_cb_kernel<<<(HH * MM * DH / 8) / 256, 256, 0, stream>>>(cb, cb_hi, cb_lo);

    dim3 gridA(NN / 128, HH);   // (128, 8) = 1024 blocks x 8 waves
    vq_assign_kernel<<<gridA, 512, 0, stream>>>(
        z, cb, cb_hi, cb_lo,
        out + OFF_ZQ, out + OFF_IDX, sse, zs);

    vq_hist_kernel<<<HH, 256, 0, stream>>>(out + OFF_IDX, counts, offsets, cursors);
    vq_scatter_kernel<<<(BZ * HH * LL) / 256, 256, 0, stream>>>(
        out + OFF_IDX, cursors, rowlist);
    vq_gather_update_kernel<<<(HH * MM) / 4, 256, 0, stream>>>(
        zs, cb, counts, offsets, rowlist, sse,
        out + OFF_CB, out + OFF_LOSS);
}